// Round 1
// baseline (196.255 us; speedup 1.0000x reference)
//
#include <hip/hip_runtime.h>

#define BB 16
#define HIMG 64
#define WIMG 64
#define CC 256
#define NHEAD 8
#define HD 32
#define NN 4096
#define PWD 65   // 2*DH+1

__device__ __forceinline__ float elu1(float x) {
    return x > 0.0f ? x + 1.0f : __expf(x);
}
__device__ __forceinline__ float sigm(float x) {
    return 1.0f / (1.0f + __expf(-x));
}

// ---------------- Kernel 1: partial kv (K_rope^T V) and ksum per 128-row chunk ----
// grid = B*32, block = 256
__global__ __launch_bounds__(256) void k1_partial(
    const float* __restrict__ x2, const float* __restrict__ x3,
    const float* __restrict__ posw, float* __restrict__ pkv,
    float* __restrict__ pksum)
{
    const int blk   = blockIdx.x;       // b*32 + chunk
    const int b     = blk >> 5;
    const int chunk = blk & 31;
    const int n0    = chunk * 128;
    const int t     = threadIdx.x;
    const int p     = t & 127;          // fixed float4 slot within a row (k:0-63, v:64-127)
    const int rbase = t >> 7;           // 0 or 1

    const int h   = t >> 5;             // compute mapping: head
    const int idx = t & 31;
    const int dt  = idx & 7;            // d-tile (4 d's each)
    const int et  = idx >> 3;           // e-tile (8 e's each)

    __shared__ float kr_lds[8][CC];
    __shared__ float v_lds[8][CC];
    __shared__ float ksum_lds[2][CC];

    float acc[4][8];
#pragma unroll
    for (int a = 0; a < 4; ++a)
#pragma unroll
        for (int e = 0; e < 8; ++e) acc[a][e] = 0.0f;
    float ks0 = 0.f, ks1 = 0.f, ks2 = 0.f, ks3 = 0.f;

    const float* x2b = x2 + (size_t)b * NN * CC;
    const float* x3b = x3 + (size_t)b * NN * CC;

    for (int s = 0; s < 16; ++s) {
        const int r0 = n0 + s * 8;
#pragma unroll
        for (int it = 0; it < 4; ++it) {
            const int row = rbase + 2 * it;   // 0..7
            const int n = r0 + row;
            if (p < 64) {
                const float4 kx = *(const float4*)(x2b + (size_t)n * CC + p * 4);
                float4 kk;
                kk.x = elu1(kx.x); kk.y = elu1(kx.y);
                kk.z = elu1(kx.z); kk.w = elu1(kx.w);
                const int ii = n >> 6, jj = n & 63;
                const float4 pv = *(const float4*)(posw +
                    (size_t)((ii + 1) * PWD + (jj + 1)) * CC + p * 4);
                float4 kr;
                kr.x = kk.x * sigm(pv.x); kr.y = kk.y * sigm(pv.y);
                kr.z = kk.z * sigm(pv.z); kr.w = kk.w * sigm(pv.w);
                *(float4*)(&kr_lds[row][p * 4]) = kr;
                ks0 += kk.x; ks1 += kk.y; ks2 += kk.z; ks3 += kk.w;
            } else {
                const int pp = p - 64;
                const float4 vx = *(const float4*)(x3b + (size_t)n * CC + pp * 4);
                *(float4*)(&v_lds[row][pp * 4]) = vx;
            }
        }
        __syncthreads();
#pragma unroll
        for (int r = 0; r < 8; ++r) {
            const float4 k4 = *(const float4*)(&kr_lds[r][h * HD + dt * 4]);
            const float4 va = *(const float4*)(&v_lds[r][h * HD + et * 8]);
            const float4 vb = *(const float4*)(&v_lds[r][h * HD + et * 8 + 4]);
            const float kd[4] = {k4.x, k4.y, k4.z, k4.w};
            const float ve[8] = {va.x, va.y, va.z, va.w, vb.x, vb.y, vb.z, vb.w};
#pragma unroll
            for (int a = 0; a < 4; ++a)
#pragma unroll
                for (int e = 0; e < 8; ++e)
                    acc[a][e] = fmaf(kd[a], ve[e], acc[a][e]);
        }
        __syncthreads();
    }

    if (p < 64) {
        ksum_lds[rbase][p * 4 + 0] = ks0;
        ksum_lds[rbase][p * 4 + 1] = ks1;
        ksum_lds[rbase][p * 4 + 2] = ks2;
        ksum_lds[rbase][p * 4 + 3] = ks3;
    }
    __syncthreads();
    pksum[(size_t)blk * CC + t] = ksum_lds[0][t] + ksum_lds[1][t];

    float* dst = pkv + (size_t)blk * (NHEAD * HD * HD);
#pragma unroll
    for (int a = 0; a < 4; ++a)
#pragma unroll
        for (int e = 0; e < 8; ++e)
            dst[h * (HD * HD) + (dt * 4 + a) * HD + (et * 8 + e)] = acc[a][e];
}

// ---------------- Kernel 2: reduce partials, fold 1/n ---------------------------
// grid = B*8192/256 = 512, block = 256
__global__ __launch_bounds__(256) void k2_reduce(
    const float* __restrict__ pkv, const float* __restrict__ pksum,
    float* __restrict__ kvf, float* __restrict__ kmean)
{
    const int gid = blockIdx.x * 256 + threadIdx.x;   // over B*8192
    const int b = gid >> 13;
    const int o = gid & 8191;
    float s = 0.f;
#pragma unroll 4
    for (int c = 0; c < 32; ++c)
        s += pkv[(size_t)(b * 32 + c) * (NHEAD * HD * HD) + o];
    kvf[gid] = s * (1.0f / NN);
    if (o < CC) {
        float ss = 0.f;
#pragma unroll 4
        for (int c = 0; c < 32; ++c)
            ss += pksum[(size_t)(b * 32 + c) * CC + o];
        kmean[b * CC + o] = ss * (1.0f / NN);
    }
}

// ---------------- Kernel 3: out = q_rope@kv * z + LePE --------------------------
// grid = B*64 (one image row each), block = 256 (one channel each)
__global__ __launch_bounds__(256) void k3_out(
    const float* __restrict__ x1, const float* __restrict__ x3,
    const float* __restrict__ posw, const float* __restrict__ kvf,
    const float* __restrict__ kmean, const float* __restrict__ lw,
    const float* __restrict__ lb, float* __restrict__ out)
{
    const int blk  = blockIdx.x;      // b*64 + irow
    const int b    = blk >> 6;
    const int irow = blk & 63;
    const int t    = threadIdx.x;     // channel c
    const int h    = t >> 5;
    const int e    = t & 31;

    __shared__ float qr_lds[64][CC];  // 64 KiB
    __shared__ float z_lds[64][8];

    // kv column for this (h, e): kv[h][0..31][e]
    float kvc[HD];
    {
        const float* kp = kvf + (size_t)b * (NHEAD * HD * HD) + h * (HD * HD) + e;
#pragma unroll
        for (int d = 0; d < HD; ++d) kvc[d] = kp[d * HD];
    }
    float wreg[9];
#pragma unroll
    for (int q = 0; q < 9; ++q) wreg[q] = lw[t * 9 + q];
    const float bias = lb[t];

    // ---- stage: gated q row into LDS + per-pixel z ----
    {
        const int p    = t & 63;       // float4 slot within a pixel's 256 channels
        const int pixo = t >> 6;       // 0..3
        const int hh   = p >> 3;       // head of this slot
        const float4 km4 = *(const float4*)(kmean + b * CC + p * 4);
        const float* x1b = x1 + ((size_t)b * NN + (size_t)irow * 64) * CC;
        const float* pwb = posw + ((size_t)(irow + 1) * PWD + 1) * CC;
        for (int s = 0; s < 16; ++s) {
            const int pix = s * 4 + pixo;
            const float4 xv = *(const float4*)(x1b + (size_t)pix * CC + p * 4);
            float4 q4;
            q4.x = elu1(xv.x); q4.y = elu1(xv.y);
            q4.z = elu1(xv.z); q4.w = elu1(xv.w);
            const float4 pv = *(const float4*)(pwb + (size_t)pix * CC + p * 4);
            float4 qr4;
            qr4.x = q4.x * sigm(pv.x); qr4.y = q4.y * sigm(pv.y);
            qr4.z = q4.z * sigm(pv.z); qr4.w = q4.w * sigm(pv.w);
            *(float4*)(&qr_lds[pix][p * 4]) = qr4;
            float zp = q4.x * km4.x + q4.y * km4.y + q4.z * km4.z + q4.w * km4.w;
            zp += __shfl_xor(zp, 1);
            zp += __shfl_xor(zp, 2);
            zp += __shfl_xor(zp, 4);
            if ((p & 7) == 0) z_lds[pix][hh] = 1.0f / (zp + 1e-6f);
        }
    }
    __syncthreads();

    // ---- compute: sliding 3x3 window for LePE + attn matvec ----
    const bool hasU = irow > 0, hasD = irow < 63;
    const float* rowU = x3 + ((size_t)b * NN + (size_t)(irow - 1) * 64) * CC + t;
    const float* rowM = x3 + ((size_t)b * NN + (size_t)irow * 64) * CC + t;
    const float* rowD = x3 + ((size_t)b * NN + (size_t)(irow + 1) * 64) * CC + t;
    float* ob = out + ((size_t)b * NN + (size_t)irow * 64) * CC + t;

    float u0, u1, u2, m0, m1, m2, d0, d1, d2;
    u0 = m0 = d0 = 0.f;
    u1 = hasU ? rowU[0] : 0.f;
    m1 = rowM[0];
    d1 = hasD ? rowD[0] : 0.f;

    for (int j = 0; j < 64; ++j) {
        if (j < 63) {
            u2 = hasU ? rowU[(size_t)(j + 1) * CC] : 0.f;
            m2 = rowM[(size_t)(j + 1) * CC];
            d2 = hasD ? rowD[(size_t)(j + 1) * CC] : 0.f;
        } else {
            u2 = m2 = d2 = 0.f;
        }
        float lepe = bias
            + wreg[0] * u0 + wreg[1] * u1 + wreg[2] * u2
            + wreg[3] * m0 + wreg[4] * m1 + wreg[5] * m2
            + wreg[6] * d0 + wreg[7] * d1 + wreg[8] * d2;

        float accv = 0.f;
        const float* qrow = &qr_lds[j][h * HD];
#pragma unroll
        for (int d4 = 0; d4 < 8; ++d4) {
            const float4 qv = *(const float4*)(qrow + d4 * 4);
            accv = fmaf(qv.x, kvc[d4 * 4 + 0], accv);
            accv = fmaf(qv.y, kvc[d4 * 4 + 1], accv);
            accv = fmaf(qv.z, kvc[d4 * 4 + 2], accv);
            accv = fmaf(qv.w, kvc[d4 * 4 + 3], accv);
        }
        ob[(size_t)j * CC] = accv * z_lds[j][h] + lepe;

        u0 = u1; u1 = u2; m0 = m1; m1 = m2; d0 = d1; d1 = d2;
    }
}

extern "C" void kernel_launch(void* const* d_in, const int* in_sizes, int n_in,
                              void* d_out, int out_size, void* d_ws, size_t ws_size,
                              hipStream_t stream) {
    const float* x1   = (const float*)d_in[0];
    const float* x2   = (const float*)d_in[1];
    const float* x3   = (const float*)d_in[2];
    const float* posw = (const float*)d_in[3];
    const float* lw   = (const float*)d_in[4];
    const float* lb   = (const float*)d_in[5];
    float* out = (float*)d_out;

    // workspace layout (floats): needs ~17.8 MB
    float* pkv   = (float*)d_ws;                      // 512 * 8192
    float* pksum = pkv + (size_t)512 * 8192;          // 512 * 256
    float* kvf   = pksum + (size_t)512 * 256;         // 16 * 8192
    float* kmean = kvf + (size_t)16 * 8192;           // 16 * 256

    k1_partial<<<BB * 32, 256, 0, stream>>>(x2, x3, posw, pkv, pksum);
    k2_reduce<<<512, 256, 0, stream>>>(pkv, pksum, kvf, kmean);
    k3_out<<<BB * 64, 256, 0, stream>>>(x1, x3, posw, kvf, kmean, lw, lb, out);
}

// Round 2
// 119.974 us; speedup vs baseline: 1.6358x; 1.6358x over previous
//
#include <hip/hip_runtime.h>

#define BB 16
#define HIMG 64
#define WIMG 64
#define CC 256
#define NHEAD 8
#define HD 32
#define NN 4096
#define PWD 65   // 2*DH+1

__device__ __forceinline__ float elu1(float x) {
    return x > 0.0f ? x + 1.0f : __expf(x);
}
__device__ __forceinline__ float sigm(float x) {
    return 1.0f / (1.0f + __expf(-x));
}

// ---------------- Kernel 1: partial kv (K_rope^T V) and ksum per chunk ----------
// grid = B * nch, block = 256. rows = NN >> nchl rows per chunk.
__global__ __launch_bounds__(256) void k1_partial(
    const float* __restrict__ x2, const float* __restrict__ x3,
    const float* __restrict__ posw, float* __restrict__ pkv,
    float* __restrict__ pksum, int nchl, int rows)
{
    const int blk   = blockIdx.x;       // b*nch + chunk
    const int b     = blk >> nchl;
    const int chunk = blk & ((1 << nchl) - 1);
    const int n0    = chunk * rows;
    const int t     = threadIdx.x;
    const int p     = t & 127;          // float4 slot (k-loaders: 0-63, v-loaders: 64-127)
    const int rbase = t >> 7;           // 0 or 1

    const int h   = t >> 5;             // compute mapping: head
    const int idx = t & 31;
    const int dt  = idx & 7;            // d-tile (4 d's each)
    const int et  = idx >> 3;           // e-tile (8 e's each)

    __shared__ float kr_lds[8][CC];
    __shared__ float v_lds[8][CC];
    __shared__ float ksum_lds[2][CC];

    float acc[4][8];
#pragma unroll
    for (int a = 0; a < 4; ++a)
#pragma unroll
        for (int e = 0; e < 8; ++e) acc[a][e] = 0.0f;
    float ks0 = 0.f, ks1 = 0.f, ks2 = 0.f, ks3 = 0.f;

    const float* x2b = x2 + (size_t)b * NN * CC;
    const float* x3b = x3 + (size_t)b * NN * CC;

    const int nstep = rows >> 3;
    for (int s = 0; s < nstep; ++s) {
        const int r0 = n0 + s * 8;
#pragma unroll
        for (int it = 0; it < 4; ++it) {
            const int row = rbase + 2 * it;   // 0..7
            const int n = r0 + row;
            if (p < 64) {
                const float4 kx = *(const float4*)(x2b + (size_t)n * CC + p * 4);
                float4 kk;
                kk.x = elu1(kx.x); kk.y = elu1(kx.y);
                kk.z = elu1(kx.z); kk.w = elu1(kx.w);
                const int ii = n >> 6, jj = n & 63;
                const float4 pv = *(const float4*)(posw +
                    (size_t)((ii + 1) * PWD + (jj + 1)) * CC + p * 4);
                float4 kr;
                kr.x = kk.x * sigm(pv.x); kr.y = kk.y * sigm(pv.y);
                kr.z = kk.z * sigm(pv.z); kr.w = kk.w * sigm(pv.w);
                *(float4*)(&kr_lds[row][p * 4]) = kr;
                ks0 += kk.x; ks1 += kk.y; ks2 += kk.z; ks3 += kk.w;
            } else {
                const int pp = p - 64;
                const float4 vx = *(const float4*)(x3b + (size_t)n * CC + pp * 4);
                *(float4*)(&v_lds[row][pp * 4]) = vx;
            }
        }
        __syncthreads();
#pragma unroll
        for (int r = 0; r < 8; ++r) {
            const float4 k4 = *(const float4*)(&kr_lds[r][h * HD + dt * 4]);
            const float4 va = *(const float4*)(&v_lds[r][h * HD + et * 8]);
            const float4 vb = *(const float4*)(&v_lds[r][h * HD + et * 8 + 4]);
            const float kd[4] = {k4.x, k4.y, k4.z, k4.w};
            const float ve[8] = {va.x, va.y, va.z, va.w, vb.x, vb.y, vb.z, vb.w};
#pragma unroll
            for (int a = 0; a < 4; ++a)
#pragma unroll
                for (int e = 0; e < 8; ++e)
                    acc[a][e] = fmaf(kd[a], ve[e], acc[a][e]);
        }
        __syncthreads();
    }

    if (p < 64) {
        ksum_lds[rbase][p * 4 + 0] = ks0;
        ksum_lds[rbase][p * 4 + 1] = ks1;
        ksum_lds[rbase][p * 4 + 2] = ks2;
        ksum_lds[rbase][p * 4 + 3] = ks3;
    }
    __syncthreads();
    pksum[(size_t)blk * CC + t] = ksum_lds[0][t] + ksum_lds[1][t];

    float* dst = pkv + (size_t)blk * (NHEAD * HD * HD);
#pragma unroll
    for (int a = 0; a < 4; ++a)
#pragma unroll
        for (int e = 0; e < 8; ++e)
            dst[h * (HD * HD) + (dt * 4 + a) * HD + (et * 8 + e)] = acc[a][e];
}

// ---------------- Kernel 2: reduce partials, fold 1/n ---------------------------
// grid = 512, block = 256
__global__ __launch_bounds__(256) void k2_reduce(
    const float* __restrict__ pkv, const float* __restrict__ pksum,
    float* __restrict__ kvf, float* __restrict__ kmean, int nch)
{
    const int gid = blockIdx.x * 256 + threadIdx.x;   // over B*8192
    const int b = gid >> 13;
    const int o = gid & 8191;
    float s = 0.f;
#pragma unroll 4
    for (int c = 0; c < nch; ++c)
        s += pkv[(size_t)(b * nch + c) * (NHEAD * HD * HD) + o];
    kvf[gid] = s * (1.0f / NN);
    if (o < CC) {
        float ss = 0.f;
#pragma unroll 4
        for (int c = 0; c < nch; ++c)
            ss += pksum[(size_t)(b * nch + c) * CC + o];
        kmean[b * CC + o] = ss * (1.0f / NN);
    }
}

// ---------------- Kernel 3: out = q_rope@kv * z + LePE --------------------------
// grid = B*128 (half image row each), block = 256 (one channel each)
__global__ __launch_bounds__(256, 4) void k3_out(
    const float* __restrict__ x1, const float* __restrict__ x3,
    const float* __restrict__ posw, const float* __restrict__ kvf,
    const float* __restrict__ kmean, const float* __restrict__ lw,
    const float* __restrict__ lb, float* __restrict__ out)
{
    const int blk  = blockIdx.x;      // b*128 + irow*2 + jh
    const int b    = blk >> 7;
    const int irow = (blk >> 1) & 63;
    const int jh   = blk & 1;
    const int j0   = jh << 5;         // 0 or 32
    const int t    = threadIdx.x;     // channel c
    const int h    = t >> 5;
    const int e    = t & 31;

    __shared__ float qr_lds[32][CC];  // 32 KiB
    __shared__ float z_lds[32][8];

    // kv column for this (h, e): kv[h][0..31][e]
    float kvc[HD];
    {
        const float* kp = kvf + (size_t)b * (NHEAD * HD * HD) + h * (HD * HD) + e;
#pragma unroll
        for (int d = 0; d < HD; ++d) kvc[d] = kp[d * HD];
    }
    float wreg[9];
#pragma unroll
    for (int q = 0; q < 9; ++q) wreg[q] = lw[t * 9 + q];
    const float bias = lb[t];

    // ---- stage: gated q half-row into LDS + per-pixel z ----
    {
        const int p    = t & 63;       // float4 slot within a pixel's 256 channels
        const int pixo = t >> 6;       // 0..3
        const int hh   = p >> 3;       // head of this slot
        const float4 km4 = *(const float4*)(kmean + b * CC + p * 4);
        const float* x1b = x1 + ((size_t)b * NN + (size_t)irow * 64 + j0) * CC;
        const float* pwb = posw + ((size_t)(irow + 1) * PWD + (j0 + 1)) * CC;
        for (int s = 0; s < 8; ++s) {
            const int pix = s * 4 + pixo;   // 0..31 (local)
            const float4 xv = *(const float4*)(x1b + (size_t)pix * CC + p * 4);
            float4 q4;
            q4.x = elu1(xv.x); q4.y = elu1(xv.y);
            q4.z = elu1(xv.z); q4.w = elu1(xv.w);
            const float4 pv = *(const float4*)(pwb + (size_t)pix * CC + p * 4);
            float4 qr4;
            qr4.x = q4.x * sigm(pv.x); qr4.y = q4.y * sigm(pv.y);
            qr4.z = q4.z * sigm(pv.z); qr4.w = q4.w * sigm(pv.w);
            *(float4*)(&qr_lds[pix][p * 4]) = qr4;
            float zp = q4.x * km4.x + q4.y * km4.y + q4.z * km4.z + q4.w * km4.w;
            zp += __shfl_xor(zp, 1);
            zp += __shfl_xor(zp, 2);
            zp += __shfl_xor(zp, 4);
            if ((p & 7) == 0) z_lds[pix][hh] = 1.0f / (zp + 1e-6f);
        }
    }
    __syncthreads();

    // ---- compute: tiles of 8 columns, batched independent loads for MLP ----
    const bool hasU = irow > 0, hasD = irow < 63;
    const float* rU = x3 + ((size_t)b * NN + (size_t)(irow - 1) * 64 + j0) * CC + t;
    const float* rM = x3 + ((size_t)b * NN + (size_t)irow * 64 + j0) * CC + t;
    const float* rD = x3 + ((size_t)b * NN + (size_t)(irow + 1) * 64 + j0) * CC + t;
    float* ob = out + ((size_t)b * NN + (size_t)irow * 64 + j0) * CC + t;

    for (int tt = 0; tt < 4; ++tt) {
        float cu[10], cm[10], cd[10];
#pragma unroll
        for (int q = 0; q < 10; ++q) {
            const int col = tt * 8 + q - 1;     // local col in [-1, 32]
            const int g   = j0 + col;           // global col in [-1, 64]
            const bool ok = (g >= 0) && (g < 64);
            const long off = (long)col * CC;
            cm[q] = ok ? rM[off] : 0.f;
            cu[q] = (ok && hasU) ? rU[off] : 0.f;
            cd[q] = (ok && hasD) ? rD[off] : 0.f;
        }
#pragma unroll
        for (int q = 0; q < 8; ++q) {
            const int jl = tt * 8 + q;          // local pixel 0..31
            float lepe = bias
                + wreg[0] * cu[q] + wreg[1] * cu[q + 1] + wreg[2] * cu[q + 2]
                + wreg[3] * cm[q] + wreg[4] * cm[q + 1] + wreg[5] * cm[q + 2]
                + wreg[6] * cd[q] + wreg[7] * cd[q + 1] + wreg[8] * cd[q + 2];

            float accv = 0.f;
            const float* qrow = &qr_lds[jl][h * HD];
#pragma unroll
            for (int d4 = 0; d4 < 8; ++d4) {
                const float4 qv = *(const float4*)(qrow + d4 * 4);
                accv = fmaf(qv.x, kvc[d4 * 4 + 0], accv);
                accv = fmaf(qv.y, kvc[d4 * 4 + 1], accv);
                accv = fmaf(qv.z, kvc[d4 * 4 + 2], accv);
                accv = fmaf(qv.w, kvc[d4 * 4 + 3], accv);
            }
            ob[(long)jl * CC] = accv * z_lds[jl][h] + lepe;
        }
    }
}

extern "C" void kernel_launch(void* const* d_in, const int* in_sizes, int n_in,
                              void* d_out, int out_size, void* d_ws, size_t ws_size,
                              hipStream_t stream) {
    const float* x1   = (const float*)d_in[0];
    const float* x2   = (const float*)d_in[1];
    const float* x3   = (const float*)d_in[2];
    const float* posw = (const float*)d_in[3];
    const float* lw   = (const float*)d_in[4];
    const float* lb   = (const float*)d_in[5];
    float* out = (float*)d_out;

    // choose chunking by available workspace (64 chunks needs ~35.4 MB)
    const size_t need64 = (((size_t)16 * 64 * 8192) + (size_t)16 * 64 * 256 +
                           (size_t)16 * 8192 + 16 * 256) * sizeof(float);
    const int nchl = (ws_size >= need64) ? 6 : 5;
    const int nch  = 1 << nchl;
    const int rows = NN >> nchl;

    float* pkv   = (float*)d_ws;                       // 16*nch * 8192
    float* pksum = pkv + (size_t)16 * nch * 8192;      // 16*nch * 256
    float* kvf   = pksum + (size_t)16 * nch * 256;     // 16 * 8192
    float* kmean = kvf + (size_t)16 * 8192;            // 16 * 256

    k1_partial<<<16 * nch, 256, 0, stream>>>(x2, x3, posw, pkv, pksum, nchl, rows);
    k2_reduce<<<512, 256, 0, stream>>>(pkv, pksum, kvf, kmean, nch);
    k3_out<<<BB * 128, 256, 0, stream>>>(x1, x3, posw, kvf, kmean, lw, lb, out);
}